// Round 12
// baseline (4648.520 us; speedup 1.0000x reference)
//
#include <hip/hip_runtime.h>

#define SS 4096
#define TT 2048

// clang native vector types: usable directly in asm "v" constraints
typedef float v4f __attribute__((ext_vector_type(4)));
typedef float v2f __attribute__((ext_vector_type(2)));
typedef unsigned u4 __attribute__((ext_vector_type(4)));

// ---------- LLC-coherent (agent) memory ops, hand-rolled ----------
// sc0 sc1 => bypass non-coherent per-XCD L2, serve at Infinity Cache.

// one dwordx4: thread's full packed-q poll slice (4 words = 8 bf16 cols)
__device__ __forceinline__ void llc_load1(const u4* p, u4& a) {
  asm volatile(
      "global_load_dwordx4 %0, %1, off sc0 sc1\n\t"
      "s_waitcnt vmcnt(0)"
      : "=&v"(a) : "v"(p) : "memory");
}

// store + vmcnt(0): the drain is LOAD-BEARING (round-8 lesson): it forces
// the write to the coherency point promptly; removing it delayed visibility
// and regressed 1.7x.
__device__ __forceinline__ void llc_storew_drain(unsigned* p, unsigned v) {
  asm volatile("global_store_dword %0, %1, off sc0 sc1\n\t"
               "s_waitcnt vmcnt(0)"
               :: "v"(p), "v"(v) : "memory");
}

// straggle side-channel: LDS bank conflict burst (active lanes -> bank 0).
// SQ_LDS_BANK_CONFLICT increments per retry pass => retry counter.
__device__ __forceinline__ void straggle_tick(int lane) {
  float dummy;
  asm volatile("ds_read_b32 %0, %1\n\t"
               "s_waitcnt lgkmcnt(0)"
               : "=v"(dummy) : "v"(lane << 7) : "memory");
  asm volatile("" :: "v"(dummy));
}

// ---------- helpers ----------

__device__ __forceinline__ unsigned short f2bf_rn(float f) {
  unsigned int u = __float_as_uint(f);
  u += 0x7FFFu + ((u >> 16) & 1u);   // RNE; sign preserved for non-huge |x|
  return (unsigned short)(u >> 16);
}

__device__ __forceinline__ float blo(unsigned w) { return __uint_as_float(w << 16); }
__device__ __forceinline__ float bhi(unsigned w) { return __uint_as_float(w & 0xFFFF0000u); }

// ---------- persistent forward recursion: TRANSPOSED GEMV, PACKED-BF16 q ----------
// 256 blocks x 512 threads (8 waves), 1 block/CU, waves_per_eu(2,2).
// r11 structure (verified, 4588us) with q packed 2xbf16 per u32:
//  - q buffer = u32 qp[2][2048]; word j holds rows (2j, 2j+1) as bf16 lo/hi.
//    Wave w of block b produces word (b<<3)+w: ONE 4B store+drain.
//  - thread tid polls cols [8tid, 8tid+8) = words [4tid,+4) = ONE dwordx4
//    (16B vs r11's 2x16B): per-step all-to-all burst halves to 2MB.
//  - each u32 word is one producer's atomic store => the word IS the
//    sentinel; retry = reload the same dwordx4 (~600cyc, vs r9's ~1200
//    sentinel+refetch).
//  - unpack = 8 shift/ANDs per thread, reused across all 16 rows.
// Poll->GEMV->butterfly->LDS partials->barrier->combine->store: identical
// to r11. Emit load stays INSIDE the poll drain (r9/r11 placement).
// Sign protocol: stored sign of step t is s_t = ((t>>1)&1)?-1:+1 (bf16 sign
// bits, both halves); readiness mask 0x80008000; output scale folds
// s_t*s_{t-1} (+ odd t, - even t); 0xAA poison is negative in both halves
// and is only ever polled where POSITIVE is expected (t=1 buffer0 reads
// step-0 data s_0=+; t=2 buffer1 reads step-1 data s_1=+) -> safe.
#define K16(X) X(0) X(1) X(2) X(3) X(4) X(5) X(6) X(7) \
               X(8) X(9) X(10) X(11) X(12) X(13) X(14) X(15)

__global__ void __launch_bounds__(512, 1) __attribute__((amdgpu_waves_per_eu(2, 2)))
hmm_fwd(const float* __restrict__ lt, const float* __restrict__ lm0,
        const float* __restrict__ emit, unsigned* qp, float* out) {
  __shared__ float part[2][8 * 17];        // padded partials, double-buffered
  __shared__ float wsum[8];
  const int b     = blockIdx.x;
  const int tid   = threadIdx.x;
  const int wave  = tid >> 6;
  const int lane  = tid & 63;
  const int row0  = (b << 4) + (wave << 1);   // this wave's 2 global rows
  const int word0 = (b << 3) + wave;          // this wave's packed q word

  // ---- "step 0": publish own packed q0 word FIRST ----
  {
    v2f m0v = *(const v2f*)(lm0 + row0);
    v2f e0v = *(const v2f*)(emit + row0);
    unsigned pw = (unsigned)f2bf_rn(__expf(m0v.x + e0v.x))
                | ((unsigned)f2bf_rn(__expf(m0v.y + e0v.y)) << 16);
    if (lane == 0) llc_storew_drain(qp + word0, pw);   // positive = s_0
  }

  // 32 named f32 E registers: eA_r = exp(lt[16b+r][8*tid .. +4]),
  //                           eB_r = exp(lt[16b+r][8*tid+4 .. +8])
#define DECL_E(r) v4f eA_##r, eB_##r;
  K16(DECL_E)
#undef DECL_E
  {
    const float* baseE = lt + ((size_t)(b << 4)) * SS + (tid << 3);
#define INIT_E(r) { \
    v4f tA = *(const v4f*)(baseE + (size_t)(r) * SS); \
    v4f tB = *(const v4f*)(baseE + (size_t)(r) * SS + 4); \
    eA_##r = (v4f){__expf(tA.x), __expf(tA.y), __expf(tA.z), __expf(tA.w)}; \
    eB_##r = (v4f){__expf(tB.x), __expf(tB.y), __expf(tB.z), __expf(tB.w)}; }
    K16(INIT_E)
#undef INIT_E
  }

  for (int t = 1; t <= TT; ++t) {
    // emit load: issued right before the poll, drained BY the poll (its
    // HBM latency doubles as the poll grace period — r9/r11 placement)
    v2f em;
    if (lane == 0) em = *(const v2f*)(emit + (size_t)t * SS + row0);

    // poll own packed slice: expected stored-sign of step t-1
    const unsigned em32 = (((t - 1) >> 1) & 1) ? 0x80008000u : 0u;
    const u4* qsrc = (const u4*)(qp + ((t - 1) & 1) * 2048) + tid;
    u4 w;
    llc_load1(qsrc, w);
    if ((((w.x ^ em32) | (w.y ^ em32) | (w.z ^ em32) | (w.w ^ em32))
         & 0x80008000u)) {
      for (;;) {
        straggle_tick(lane);   // side-channel: count this pass
        llc_load1(qsrc, w);
        if (!(((w.x ^ em32) | (w.y ^ em32) | (w.z ^ em32) | (w.w ^ em32))
              & 0x80008000u)) break;
      }
    }
    // unpack RAW (sign s_{t-1} kept; folded into output scale)
    v4f va = {blo(w.x), bhi(w.x), blo(w.y), bhi(w.y)};
    v4f vb = {blo(w.z), bhi(w.z), blo(w.w), bhi(w.w)};

    // transposed GEMV straight from registers: 16 row-partials over own 8 cols
#define DECL_H(r) float h##r;
    K16(DECL_H)
#undef DECL_H
#define GEMV_R(r) { \
    v4f p = eA_##r * va + eB_##r * vb; \
    h##r = (p.x + p.y) + (p.z + p.w); }
    K16(GEMV_R)
#undef GEMV_R

    // reduce-scatter butterfly: after masks {32,16,8,4}, lane 4r holds row r
    // summed over this wave's 64 lanes; masks {2,1} broadcast within quads.
    const bool b5 = (lane & 32) != 0;
    const bool b4 = (lane & 16) != 0;
    const bool b3 = (lane & 8) != 0;
    const bool b2 = (lane & 4) != 0;
    float n0, n1, n2, n3, n4, n5, n6, n7;
#define RS32(i, A, B) { \
    float kk = b5 ? (B) : (A); \
    float ss = b5 ? (A) : (B); \
    n##i = kk + __shfl_xor(ss, 32); }
    RS32(0, h0, h8)  RS32(1, h1, h9)  RS32(2, h2, h10) RS32(3, h3, h11)
    RS32(4, h4, h12) RS32(5, h5, h13) RS32(6, h6, h14) RS32(7, h7, h15)
#undef RS32
    float mm0, mm1, mm2, mm3;
#define RS16(i, A, B) { \
    float kk = b4 ? (B) : (A); \
    float ss = b4 ? (A) : (B); \
    mm##i = kk + __shfl_xor(ss, 16); }
    RS16(0, n0, n4) RS16(1, n1, n5) RS16(2, n2, n6) RS16(3, n3, n7)
#undef RS16
    float pp0, pp1;
#define RS8(i, A, B) { \
    float kk = b3 ? (B) : (A); \
    float ss = b3 ? (A) : (B); \
    pp##i = kk + __shfl_xor(ss, 8); }
    RS8(0, mm0, mm2) RS8(1, mm1, mm3)
#undef RS8
    float s = (b2 ? pp1 : pp0) + __shfl_xor(b2 ? pp0 : pp1, 4);
    s += __shfl_xor(s, 2);
    s += __shfl_xor(s, 1);

    // 16 writer lanes (lane = 4r) publish wave-partial for local row r
    if (!(lane & 3)) part[t & 1][wave * 17 + (lane >> 2)] = s;
    __syncthreads();   // single barrier per step (partials double-buffered)

    // wave w combines 8 wave-partials for its rows 2w, 2w+1
    const float* pb = part[t & 1];
    float x = pb[(lane & 7) * 17 + (wave << 1) + ((lane >> 3) & 1)];
    x += __shfl_xor(x, 1);
    x += __shfl_xor(x, 2);
    x += __shfl_xor(x, 4);          // lanes 0-7: S(2w); lanes 8-15: S(2w+1)
    float y = __shfl_xor(x, 8);     // lane 0 receives S(2w+1)

    if (lane == 0) {
      float scale = ((t & 255) == 0) ? 0x1p-46f : 1.0f;  // exact pow2 renorm
      if (!(t & 1)) scale = -scale;                       // s_t * s_{t-1}
      float rx = x * (__expf(em.x) * scale);
      float ry = y * (__expf(em.y) * scale);
      unsigned pw = (unsigned)f2bf_rn(rx) | ((unsigned)f2bf_rn(ry) << 16);
      llc_storew_drain(qp + (t & 1) * 2048 + word0, pw);
    }
  }

  // final reduction: q_T (t=2048) in buffer 0, stored sign positive
  if (b == 0) {
    const u4* qf = (const u4*)qp + tid;   // 512 threads x 4 words = 2048
    u4 w;
    for (;;) {
      llc_load1(qf, w);
      if (!((w.x | w.y | w.z | w.w) & 0x80008000u)) break;
    }
    float s = blo(w.x) + bhi(w.x) + blo(w.y) + bhi(w.y)
            + blo(w.z) + bhi(w.z) + blo(w.w) + bhi(w.w);
#pragma unroll
    for (int m = 32; m > 0; m >>= 1) s += __shfl_xor(s, m);
    if (lane == 0) wsum[wave] = s;
    __syncthreads();
    if (tid == 0) {
      float tot = 0.f;
#pragma unroll
      for (int i = 0; i < 8; ++i) tot += wsum[i];
      out[0] = logf(tot) + 368.0f * 0.693147180559945f;   // 8 rescales * 46 * ln2
    }
  }
}

// ---------- launch ----------
extern "C" void kernel_launch(void* const* d_in, const int* in_sizes, int n_in,
                              void* d_out, int out_size, void* d_ws, size_t ws_size,
                              hipStream_t stream) {
  const float* log_M0    = (const float*)d_in[0];
  const float* log_trans = (const float*)d_in[1];
  const float* log_emit  = (const float*)d_in[2];
  // d_in[3] = T (fixed 2048, unused)

  unsigned* qp = (unsigned*)d_ws;   // 2 x 8 KiB packed bf16 (0xAA poison = negative)
  float* out   = (float*)d_out;

  hipLaunchKernelGGL(hmm_fwd, dim3(256), dim3(512), 0, stream,
                     log_trans, log_M0, log_emit, qp, out);
}